// Round 3
// baseline (272.937 us; speedup 1.0000x reference)
//
#include <hip/hip_runtime.h>
#include <hip/hip_bf16.h>
#include <stdint.h>

// out = x @ (W_shared + W_expert)^T + bias   (MoE collapses: positional routing,
// shared expert weights, normalized top-2 gate weights sum to 1)
static constexpr int Mdim = 16384;  // T = B*N tokens
static constexpr int Ndim = 1024;
static constexpr int Kdim = 1024;
static constexpr int BM = 128, BN = 128, BK = 32;
static constexpr int NT = Kdim / BK;  // 32 k-tiles

typedef __attribute__((ext_vector_type(8))) __bf16 bf16x8;
typedef __attribute__((ext_vector_type(4))) float f32x4;
typedef __attribute__((ext_vector_type(8))) unsigned short ushort8;

__device__ inline unsigned short f2bf_rn(float f) {
    union { float f; uint32_t u; } v; v.f = f;
    uint32_t u = v.u;
    uint32_t r = u + 0x7FFFu + ((u >> 16) & 1u);
    return (unsigned short)(r >> 16);
}

// two fp32 -> packed bf16 pair (round-half-up; ties-only deviation from RNE,
// absmax headroom is 3x)
__device__ inline uint32_t pack_bf2(float a, float b) {
    union { float f; uint32_t u; } ua, ub;
    ua.f = a; ub.f = b;
    uint32_t x = ua.u + 0x8000u;
    uint32_t y = ub.u + 0x8000u;
    return (x >> 16) | (y & 0xFFFF0000u);
}

// Wc = bf16(W_shared + W_expert), RNE, 8 elems/thread
__global__ __launch_bounds__(256) void cvt_w_kernel(const float* __restrict__ ws,
                                                    const float* __restrict__ we,
                                                    unsigned short* __restrict__ wc) {
    const size_t i = ((size_t)blockIdx.x * 256 + threadIdx.x) * 8;
    const f32x4* p0 = (const f32x4*)(ws + i);
    const f32x4* p1 = (const f32x4*)(we + i);
    f32x4 a0 = p0[0], a1 = p0[1], b0 = p1[0], b1 = p1[1];
    ushort8 o;
    o[0] = f2bf_rn(a0[0] + b0[0]); o[1] = f2bf_rn(a0[1] + b0[1]);
    o[2] = f2bf_rn(a0[2] + b0[2]); o[3] = f2bf_rn(a0[3] + b0[3]);
    o[4] = f2bf_rn(a1[0] + b1[0]); o[5] = f2bf_rn(a1[1] + b1[1]);
    o[6] = f2bf_rn(a1[2] + b1[2]); o[7] = f2bf_rn(a1[3] + b1[3]);
    *(ushort8*)(wc + i) = o;
}

__device__ inline void gload16(const void* g, void* l) {
    __builtin_amdgcn_global_load_lds((const __attribute__((address_space(1))) void*)g,
                                     (__attribute__((address_space(3))) void*)l,
                                     16, 0, 0);
}

// Software-pipelined GEMM, 1 barrier/iteration, double-buffered LDS (32 KiB).
//  - B (bf16 W) staged via global_load_lds at prefetch distance 1 (L2-resident,
//    ~200-300 cyc, hidden behind the compute phase).
//  - A (fp32 X) loaded to VGPRs at prefetch distance 2 (HBM ~900 cyc, fully
//    hidden: consumed by convert+ds_write one full iteration after issue).
//    Plain global->VGPR loads carry no cross-wave visibility, so the barrier
//    only has to drain the B DMA and the A ds_writes of the *previous* iter.
__global__ __launch_bounds__(256, 3) void gemm_pipe(const float* __restrict__ X,
                                                    const unsigned short* __restrict__ Bt,
                                                    const float* __restrict__ bias,
                                                    float* __restrict__ C) {
    __shared__ unsigned short As[2][BM * BK];  // 2 x 8 KiB
    __shared__ unsigned short Bs[2][BN * BK];  // 2 x 8 KiB

    const int tid = threadIdx.x;
    const int wave = tid >> 6;
    const int lane = tid & 63;
    const int bid = blockIdx.x;
    const int bm = bid & 127;   // bm-fastest: all 8 bn-sharers of an A-stripe on one XCD
    const int bn = bid >> 7;
    const int wm = (wave >> 1) * 64;
    const int wn = (wave & 1) * 64;

    // ---- B staging map (global_load_lds: wave-uniform base + lane*16) ----
    const int cw0 = wave, cw1 = wave + 4;      // 1-KiB chunks = 16 rows each
    const int brow0 = cw0 * 16 + (lane >> 2);
    const int brow1 = cw1 * 16 + (lane >> 2);
    const int bcol = (lane & 3) * 8;
    const unsigned short* gB0 = Bt + (size_t)(bn * BN + brow0) * Kdim + bcol;
    const unsigned short* gB1 = Bt + (size_t)(bn * BN + brow1) * Kdim + bcol;

    // ---- A staging map (fp32 -> VGPR -> bf16 -> LDS) ----
    const int arow = tid >> 3;     // 0..31, plus u*32
    const int acol4 = tid & 7;     // float4 index within the 32-col tile
    const float* gA = X + (size_t)(bm * BM + arow) * Kdim + acol4 * 4;

    const int fr = lane & 15;
    const int fq = lane >> 4;
    const int fk = fq * 8;

    f32x4 av[2][4];  // two in-flight A register sets (prefetch distance 2)

    auto issueA = [&](int t, int s) {
#pragma unroll
        for (int u = 0; u < 4; ++u)
            av[s][u] = *(const f32x4*)(gA + (size_t)u * 32 * Kdim + t * BK);
    };
    auto issueB = [&](int t, int buf) {
        gload16(gB0 + t * BK, &Bs[buf][cw0 * 512 + lane * 8]);
        gload16(gB1 + t * BK, &Bs[buf][cw1 * 512 + lane * 8]);
    };
    auto writeA = [&](int s, int buf) {
#pragma unroll
        for (int u = 0; u < 4; ++u) {
            uint2 w;
            w.x = pack_bf2(av[s][u][0], av[s][u][1]);
            w.y = pack_bf2(av[s][u][2], av[s][u][3]);
            *(uint2*)(&As[buf][(arow + u * 32) * BK + acol4 * 4]) = w;
        }
    };

    f32x4 acc[4][4] = {};

    // Prologue: tile 0 fully staged; tile 1's A loads in flight.
    issueB(0, 0);
    issueA(0, 0);
    issueA(1, 1);
    writeA(0, 0);   // one-time exposed wait on av[0]

    for (int t = 0; t < NT; ++t) {
        const int cur = t & 1, nxt = cur ^ 1;
        __syncthreads();  // drains B DMA(t) + A ds_writes(t) issued last iter;
                          // guarantees buf `nxt` is no longer being read
        if (t + 1 < NT) issueB(t + 1, nxt);
        if (t + 2 < NT) issueA(t + 2, t & 1);       // set freed when A(t) was written
        if (t + 1 < NT) writeA((t + 1) & 1, nxt);   // data issued a full iter ago

        bf16x8 af[4], bfr[4];
#pragma unroll
        for (int i = 0; i < 4; ++i)
            af[i] = *(const bf16x8*)(&As[cur][(wm + i * 16 + fr) * BK + fk]);
#pragma unroll
        for (int j = 0; j < 4; ++j)
            bfr[j] = *(const bf16x8*)(&Bs[cur][(wn + j * 16 + fr) * BK + fk]);
#pragma unroll
        for (int i = 0; i < 4; ++i)
#pragma unroll
            for (int j = 0; j < 4; ++j)
                acc[i][j] = __builtin_amdgcn_mfma_f32_16x16x32_bf16(af[i], bfr[j], acc[i][j], 0, 0, 0);
    }

    // Epilogue: C/D layout col = lane&15, row = (lane>>4)*4 + reg  [m89-verified]
#pragma unroll
    for (int j = 0; j < 4; ++j) {
        const int col = bn * BN + wn + j * 16 + fr;
        const float bv = bias[col];
#pragma unroll
        for (int i = 0; i < 4; ++i) {
            const int row = bm * BM + wm + i * 16 + fq * 4;
            float* p = C + (size_t)row * Ndim + col;
#pragma unroll
            for (int r = 0; r < 4; ++r)
                p[(size_t)r * Ndim] = acc[i][j][r] + bv;
        }
    }
}

extern "C" void kernel_launch(void* const* d_in, const int* in_sizes, int n_in,
                              void* d_out, int out_size, void* d_ws, size_t ws_size,
                              hipStream_t stream) {
    // inputs: x, cond, mask, W_shared, W_expert, W_gate, bias
    const float* x    = (const float*)d_in[0];
    const float* Wsh  = (const float*)d_in[3];
    const float* Wex  = (const float*)d_in[4];
    const float* bias = (const float*)d_in[6];
    float* out = (float*)d_out;

    unsigned short* Wbf = (unsigned short*)d_ws;  // 1024*1024 bf16 = 2 MiB

    hipLaunchKernelGGL(cvt_w_kernel, dim3((Ndim * Kdim) / (256 * 8)), dim3(256), 0, stream,
                       Wsh, Wex, Wbf);
    hipLaunchKernelGGL(gemm_pipe, dim3((Mdim / BM) * (Ndim / BN)), dim3(256), 0, stream,
                       x, Wbf, bias, out);
}